// Round 2
// baseline (713.585 us; speedup 1.0000x reference)
//
#include <hip/hip_runtime.h>
#include <math.h>

// Problem constants
#define NROWS 32768       // B*H*W
#define KCODES 1024
#define DDIM 256
#define BM 32             // rows per block
#define CCHUNK 512        // cols per chunk (2 chunks cover K=1024)
#define DK 16             // K-dimension slice staged in LDS
#define QUANT_OFF 1       // out offsets: loss@0, quant@1
#define PERP_OFF  8388609
#define ENC_OFF   8388610

// ws layout (floats): [0,1024) e2 norms, [1024,2048) counts, [2048] kld_sum, [2049] elat_sum

__global__ void __launch_bounds__(256)
vq_setup(const float* __restrict__ emb, float* __restrict__ ws) {
    int k = blockIdx.x * 256 + threadIdx.x;
    if (k < KCODES) {
        const float* row = emb + (size_t)k * DDIM;
        float s = 0.f;
        #pragma unroll 4
        for (int c = 0; c < DDIM; c += 4) {
            float4 v = *(const float4*)(row + c);
            s = fmaf(v.x, v.x, s); s = fmaf(v.y, v.y, s);
            s = fmaf(v.z, v.z, s); s = fmaf(v.w, v.w, s);
        }
        ws[k] = s;
        ws[KCODES + k] = 0.f;
        if (k == 0) { ws[2 * KCODES] = 0.f; ws[2 * KCODES + 1] = 0.f; }
    }
}

__global__ void __launch_bounds__(256)
vq_main(const float* __restrict__ inp, const float* __restrict__ emb,
        const float* __restrict__ gmb, float* __restrict__ out,
        float* __restrict__ ws) {
    // xs[d][row]: x slice; read as full-wave broadcast (1 addr/wave) -> bank-free
    // es[d][code]: e slice; read as contiguous b128 across 64 lanes
    __shared__ __align__(16) float xs[DK][BM + 4];        // 2.3 KB
    __shared__ __align__(16) float es[DK][CCHUNK + 4];    // 33 KB
    __shared__ float xn2p[8][BM];
    __shared__ float xn2[BM];
    __shared__ int   idxs[BM];
    __shared__ float redK[4], redE[4];

    const int tid = threadIdx.x;
    const int ct  = tid & 63;   // col-thread 0..63 (one wave = one rt, all ct)
    const int rt  = tid >> 6;   // row-thread 0..3, 8 rows each
    const int n0  = blockIdx.x * BM;
    const int b   = n0 >> 10;   // HW = 1024 spatial per batch; block never straddles
    const int s0  = n0 & 1023;

    const float* e2     = ws;
    float*       counts = ws + KCODES;

    // ---- xn2 pre-pass: 8 partials per row, coalesced along s
    {
        int r = tid & 31, h = tid >> 5;
        const float* base = inp + ((size_t)(b * DDIM + h * 32) << 10) + s0 + r;
        float s = 0.f;
        #pragma unroll 4
        for (int c = 0; c < 32; ++c) { float v = base[(size_t)c << 10]; s = fmaf(v, v, s); }
        xn2p[h][r] = s;
    }
    __syncthreads();
    if (tid < BM) {
        float s = 0.f;
        #pragma unroll
        for (int p = 0; p < 8; ++p) s += xn2p[p][tid];
        xn2[tid] = s;
    }
    // (published by the barriers inside the K loop well before first epilogue use)

    float kld_acc = 0.f;
    float runval[8];
    int   runidx[8];
    #pragma unroll
    for (int i = 0; i < 8; ++i) { runval[i] = -1e30f; runidx[i] = 0; }

    for (int kc = 0; kc < KCODES / CCHUNK; ++kc) {
        const int c0 = kc * CCHUNK;
        float acc[8][8];
        #pragma unroll
        for (int i = 0; i < 8; ++i)
            #pragma unroll
            for (int j = 0; j < 8; ++j) acc[i][j] = 0.f;

        for (int kch = 0; kch < DDIM / DK; ++kch) {
            const int d0 = kch * DK;
            __syncthreads();
            // stage xs: 16 x 32 floats = 128 float4 (threads 0..127)
            if (tid < 128) {
                int d = tid >> 3, r4 = (tid & 7) * 4;
                const float* xb = inp + ((size_t)(b * DDIM + d0 + d) << 10) + s0 + r4;
                *(float4*)&xs[d][r4] = *(const float4*)xb;
            }
            // stage es: es[d][code] = emb[c0+code][d0+d], 16x512 floats = 2048 float4
            {
                const float* ebb = emb + (size_t)c0 * DDIM + d0;
                #pragma unroll
                for (int t = 0; t < 8; ++t) {
                    int u = tid + 256 * t;        // 0..2047
                    int code = u >> 2, j = u & 3;
                    float4 v = *(const float4*)(ebb + (size_t)code * DDIM + j * 4);
                    es[j * 4 + 0][code] = v.x;
                    es[j * 4 + 1][code] = v.y;
                    es[j * 4 + 2][code] = v.z;
                    es[j * 4 + 3][code] = v.w;
                }
            }
            __syncthreads();
            #pragma unroll
            for (int d = 0; d < DK; ++d) {
                float4 x0 = *(const float4*)&xs[d][rt * 8];      // wave-broadcast
                float4 x1 = *(const float4*)&xs[d][rt * 8 + 4];
                float4 e0 = *(const float4*)&es[d][ct * 8];      // contiguous b128
                float4 e1 = *(const float4*)&es[d][ct * 8 + 4];
                float xr[8] = {x0.x, x0.y, x0.z, x0.w, x1.x, x1.y, x1.z, x1.w};
                float ec[8] = {e0.x, e0.y, e0.z, e0.w, e1.x, e1.y, e1.z, e1.w};
                #pragma unroll
                for (int i = 0; i < 8; ++i)
                    #pragma unroll
                    for (int j = 0; j < 8; ++j)
                        acc[i][j] = fmaf(xr[i], ec[j], acc[i][j]);
            }
        }

        // ---- epilogue for this 512-col chunk: dist, gumbel argmax, KLD
        #pragma unroll
        for (int i = 0; i < 8; ++i) {
            int row = rt * 8 + i;
            float xn = xn2[row];
            const float* grow = gmb + ((size_t)(n0 + row) << 10) + c0 + ct * 8;
            float4 g0 = *(const float4*)(grow);
            float4 g1 = *(const float4*)(grow + 4);
            float gv[8] = {g0.x, g0.y, g0.z, g0.w, g1.x, g1.y, g1.z, g1.w};
            #pragma unroll
            for (int j = 0; j < 8; ++j) {
                int col = c0 + ct * 8 + j;
                float dist = xn + e2[col] - 2.f * acc[i][j];
                float val  = gv[j] - dist;
                if (val > runval[i]) { runval[i] = val; runidx[i] = col; } // cols ascend
                float p = 1.f / (1.f + __expf(dist));
                kld_acc += p * __logf(fmaxf(p, 1e-8f));
            }
        }
    }

    // ---- argmax reduce across the 64 col-lanes (first-index tie-break)
    #pragma unroll
    for (int i = 0; i < 8; ++i) {
        float v = runval[i];
        int   c = runidx[i];
        #pragma unroll
        for (int off = 32; off > 0; off >>= 1) {
            float ov = __shfl_xor(v, off);
            int   oc = __shfl_xor(c, off);
            if (ov > v || (ov == v && oc < c)) { v = ov; c = oc; }
        }
        if (ct == 0) {
            idxs[rt * 8 + i] = c;
            atomicAdd(&counts[c], 1.0f);
        }
    }
    __syncthreads();

    // ---- encodings: one-hot, coalesced float4 stores
    {
        float* enc = out + ENC_OFF;
        for (int t = tid; t < BM * (KCODES / 4); t += 256) {
            int c4 = t & 255, row = t >> 8;
            int base = c4 * 4;
            int id = idxs[row];
            float4 v;
            v.x = (base + 0 == id) ? 1.f : 0.f;
            v.y = (base + 1 == id) ? 1.f : 0.f;
            v.z = (base + 2 == id) ? 1.f : 0.f;
            v.w = (base + 3 == id) ? 1.f : 0.f;
            *(float4*)(enc + ((size_t)(n0 + row) << 10) + base) = v;
        }
    }

    // ---- quantized gather + store (NCHW) + e_latent partial
    float elat_acc = 0.f;
    {
        float* outq = out + QUANT_OFF;
        for (int t = tid; t < DDIM * (BM / 4); t += 256) {  // (c, r4)
            int r4 = t & 7, c = t >> 3;
            float4 xv = *(const float4*)(inp + ((size_t)(b * DDIM + c) << 10) + s0 + r4 * 4);
            float q0 = emb[(size_t)idxs[r4 * 4 + 0] * DDIM + c];
            float q1 = emb[(size_t)idxs[r4 * 4 + 1] * DDIM + c];
            float q2 = emb[(size_t)idxs[r4 * 4 + 2] * DDIM + c];
            float q3 = emb[(size_t)idxs[r4 * 4 + 3] * DDIM + c];
            float d0 = q0 - xv.x, d1 = q1 - xv.y, d2 = q2 - xv.z, d3 = q3 - xv.w;
            elat_acc = fmaf(d0, d0, elat_acc);
            elat_acc = fmaf(d1, d1, elat_acc);
            elat_acc = fmaf(d2, d2, elat_acc);
            elat_acc = fmaf(d3, d3, elat_acc);
            float4 qv = make_float4(q0, q1, q2, q3);
            *(float4*)(outq + (((size_t)(b * DDIM + c)) << 10) + s0 + r4 * 4) = qv;
        }
    }

    // ---- block-reduce kld & elat, one atomic each per block
    #pragma unroll
    for (int off = 32; off > 0; off >>= 1) {
        kld_acc  += __shfl_xor(kld_acc, off);
        elat_acc += __shfl_xor(elat_acc, off);
    }
    int wave = tid >> 6;
    if ((tid & 63) == 0) { redK[wave] = kld_acc; redE[wave] = elat_acc; }
    __syncthreads();
    if (tid == 0) {
        atomicAdd(&ws[2 * KCODES],     redK[0] + redK[1] + redK[2] + redK[3]);
        atomicAdd(&ws[2 * KCODES + 1], redE[0] + redE[1] + redE[2] + redE[3]);
    }
}

__global__ void __launch_bounds__(256)
vq_finalize(const float* __restrict__ ws, float* __restrict__ out) {
    __shared__ float red[4];
    int tid = threadIdx.x;
    float s = 0.f;
    for (int k = tid; k < KCODES; k += 256) {
        float avg = ws[KCODES + k] * (1.f / (float)NROWS);
        s += avg * logf(avg + 1e-10f);
    }
    #pragma unroll
    for (int off = 32; off > 0; off >>= 1) s += __shfl_xor(s, off);
    if ((tid & 63) == 0) red[tid >> 6] = s;
    __syncthreads();
    if (tid == 0) {
        float ssum = red[0] + red[1] + red[2] + red[3];
        float perp = expf(-ssum);
        float kld  = ws[2 * KCODES]     / (float)NROWS;
        float elat = ws[2 * KCODES + 1] / (float)(NROWS * DDIM);
        float ratio = kld / fmaxf(elat, 1e-8f);
        float loss  = 1.5f * (kld + elat * ratio);
        out[0]        = loss;
        out[PERP_OFF] = perp;
    }
}

extern "C" void kernel_launch(void* const* d_in, const int* in_sizes, int n_in,
                              void* d_out, int out_size, void* d_ws, size_t ws_size,
                              hipStream_t stream) {
    const float* inp = (const float*)d_in[0];   // [32,256,32,32]
    const float* emb = (const float*)d_in[1];   // [1024,256]
    const float* gmb = (const float*)d_in[2];   // [32768,1024]
    float* out = (float*)d_out;
    float* ws  = (float*)d_ws;

    vq_setup<<<dim3(KCODES / 256), dim3(256), 0, stream>>>(emb, ws);
    vq_main<<<dim3(NROWS / BM), dim3(256), 0, stream>>>(inp, emb, gmb, out, ws);
    vq_finalize<<<dim3(1), dim3(256), 0, stream>>>(ws, out);
}